// Round 1
// baseline (101.449 us; speedup 1.0000x reference)
//
#include <hip/hip_runtime.h>
#include <cstddef>

#define EPS 1e-6f
constexpr float INV_SQRT_E = 0.6065306597126334f;  // exp(-0.5*THETA^2), THETA=1

// R14: LDS width-vectorization of the R12 structure (kernel is LDS-issue bound,
// ~93 b32-equiv LDS instrs/px D-summed; b64 costs ~same issue slot as b32).
//  1. Staging: paired ds_write_b64 to both planes (LW even -> pairs never
//     cross rows).
//  2. Vertical stage: column-PAIR float2 ladders, plane-split (sx pass then
//     slg pass) to cap live accumulators; b128 cs2 + b64 cs1 writes.
//  3. SAD: D even -> vertical-pair x horizontal-pair, ds_read_b64 ladders,
//     4 px/owner (ty<4 && tx<32). D=3 keeps the R12 b32 pair-walk (odd
//     stride breaks b64 alignment). D=1 keeps the register path.
// Config: block (64,8), TH=8, LDS 39,936 B -> 4 blocks/CU = 32 waves/CU.
template <int D>
__device__ __forceinline__ void body(const float* __restrict__ x,
                                     float* __restrict__ out,
                                     char* smem, int bc, int H, int W)
{
    constexpr int PAD = D * D;          // halo per side
    constexpr int KS  = 2 * D + 1;      // taps per axis
    constexpr int K   = KS * KS;        // patch size
    constexpr int TW  = 64, TH = 8;
    constexpr int LW  = TW + 2 * PAD;   // always even (TW=64, 2*PAD even)
    constexpr int LH  = TH + 2 * PAD;
    constexpr int NE  = LH * LW;        // always even
    constexpr int NI2 = (NE + 1023) / 1024;
    constexpr float INVK = 1.0f / (float)K;
    constexpr float UNB  = (float)K / (float)(K - 1);

    float*  sx  = (float*)smem;                 // [NE] v
    float*  slg = sx + NE;                      // [NE] v*log(v+eps)
    float2* cs2 = (float2*)(slg + NE);          // [TH*LW] {col_s, col_s2}
    float*  cs1 = (float*)(cs2 + TH * LW);      // [TH*LW] col_sl
    // Aliased exchange planes (cs2 region is dead after the horizontal stage;
    // needs 4096 B, cs2 has >= 4608 B for D>=2).
    float*  muP  = (float*)cs2;                 // [TH*64]
    float*  sadP = muP + TH * 64;               // [TH*64]

    const int w0 = blockIdx.x * TW;
    const int h0 = blockIdx.y * TH;
    const float* xp = x + (size_t)bc * H * W;
    const int tid = threadIdx.y * 64 + threadIdx.x;

    // ---- Staging: batched global loads (element pairs), b64 LDS writes. ----
    float v0b[NI2], v1b[NI2];
    #pragma unroll
    for (int i = 0; i < NI2; ++i) {
        const int e0 = 2 * (tid + i * 512);
        float v0 = 0.0f, v1 = 0.0f;
        if (e0 < NE) {
            const int r  = e0 / LW;          // e0, LW even -> cc even
            const int cc = e0 - r * LW;
            const int gh = h0 - PAD + r;
            const int gw = w0 - PAD + cc;
            if (gh >= 0 && gh < H) {
                if (gw >= 0 && gw < W)          v0 = xp[gh * W + gw];
                if (gw + 1 >= 0 && gw + 1 < W)  v1 = xp[gh * W + gw + 1];
            }
        }
        v0b[i] = v0; v1b[i] = v1;
    }
    #pragma unroll
    for (int i = 0; i < NI2; ++i) {
        const int e0 = 2 * (tid + i * 512);
        if (e0 < NE) {
            *(float2*)&sx[e0]  = make_float2(v0b[i], v1b[i]);
            *(float2*)&slg[e0] = make_float2(v0b[i] * __logf(v0b[i] + EPS),
                                             v1b[i] * __logf(v1b[i] + EPS));
        }
    }
    __syncthreads();

    const int tx = threadIdx.x;
    const int ty = threadIdx.y;

    if constexpr (K <= 9) {
        // ---- D=1: single pass, taps cached in registers. ----
        const float* bx = sx  + ty * LW + tx;
        const float* bl = slg + ty * LW + tx;
        float s = 0.f, s2 = 0.f, sl = 0.f, ta[K];
        #pragma unroll
        for (int mi = 0; mi < KS; ++mi)
            #pragma unroll
            for (int mj = 0; mj < KS; ++mj) {
                const float v = bx[mi * LW + mj];
                ta[mi * KS + mj] = v;
                s  += v;
                s2  = fmaf(v, v, s2);
                sl += bl[mi * LW + mj];
            }
        const float mu = s * INVK;
        float sad = 0.f;
        #pragma unroll
        for (int i = 0; i < K; ++i) sad += fabsf(ta[i] - mu);

        const float energy   = s2 * INVK;
        const float var      = fmaxf(energy - mu * mu, 0.f);
        const float sd       = sqrtf(var * UNB) + EPS;
        const float contrast = var / (sd * sd);
        const float entropy  = -sl * INVK;
        const float homog    = 1.f / (1.f + sad * INVK);
        const size_t fs = (size_t)H * W;
        const size_t ro = (size_t)(h0 + ty) * W;
        float* op = out + (size_t)bc * 4 * fs + w0 + tx;
        __builtin_nontemporal_store((contrast + EPS) * INV_SQRT_E, &op[0 * fs + ro]);
        __builtin_nontemporal_store((energy   + EPS) * INV_SQRT_E, &op[1 * fs + ro]);
        __builtin_nontemporal_store((entropy  + EPS) * INV_SQRT_E, &op[2 * fs + ro]);
        __builtin_nontemporal_store((homog    + EPS) * INV_SQRT_E, &op[3 * fs + ro]);
        return;
    } else {
        // ---- Vertical stage: column-PAIR (b64) pair-walk. Row pairs:
        //  D=2: (0,2)(1,3)(4,6)(5,7)  D=3: (0,3)(1,4)(2,5)+{6,7} indep
        //  D=4: (0,4)(1,5)(2,6)(3,7)
        constexpr int HW2 = LW / 2;
        if (tid < 4 * HW2) {
            const int p  = tid / HW2;
            const int c2 = (tid - p * HW2) * 2;
            if (!(D == 3 && p == 3)) {
                const int vA = (D == 2) ? ((p < 2) ? p : p + 2) : p;
                const int vB = vA + D;
                // pass 1: sx (sum + sumsq), 8 live accumulators
                const float2* cx = (const float2*)(sx + vA * LW + c2);
                float sA0=0,sA1=0,qA0=0,qA1=0,sB0=0,sB1=0,qB0=0,qB1=0;
                #pragma unroll
                for (int t = 0; t <= KS; ++t) {
                    const float2 v = cx[t * D * HW2];
                    if (t < KS) { sA0 += v.x; sA1 += v.y;
                                  qA0 = fmaf(v.x,v.x,qA0); qA1 = fmaf(v.y,v.y,qA1); }
                    if (t >= 1) { sB0 += v.x; sB1 += v.y;
                                  qB0 = fmaf(v.x,v.x,qB0); qB1 = fmaf(v.y,v.y,qB1); }
                }
                // pass 2: slg, 4 live accumulators
                const float2* cl = (const float2*)(slg + vA * LW + c2);
                float lA0=0,lA1=0,lB0=0,lB1=0;
                #pragma unroll
                for (int t = 0; t <= KS; ++t) {
                    const float2 g = cl[t * D * HW2];
                    if (t < KS) { lA0 += g.x; lA1 += g.y; }
                    if (t >= 1) { lB0 += g.x; lB1 += g.y; }
                }
                *(float4*)&cs2[vA * LW + c2] = make_float4(sA0, qA0, sA1, qA1);
                *(float4*)&cs2[vB * LW + c2] = make_float4(sB0, qB0, sB1, qB1);
                *(float2*)&cs1[vA * LW + c2] = make_float2(lA0, lA1);
                *(float2*)&cs1[vB * LW + c2] = make_float2(lB0, lB1);
            } else {            // D=3 leftover rows 6,7: independent col-pair walks
                #pragma unroll
                for (int rr = 6; rr <= 7; ++rr) {
                    const float2* cx = (const float2*)(sx  + rr * LW + c2);
                    const float2* cl = (const float2*)(slg + rr * LW + c2);
                    float s0=0,s1=0,q0=0,q1=0,l0=0,l1=0;
                    #pragma unroll
                    for (int mi = 0; mi < KS; ++mi) {
                        const float2 v = cx[mi * D * HW2];
                        const float2 g = cl[mi * D * HW2];
                        s0 += v.x; s1 += v.y;
                        q0 = fmaf(v.x,v.x,q0); q1 = fmaf(v.y,v.y,q1);
                        l0 += g.x; l1 += g.y;
                    }
                    *(float4*)&cs2[rr * LW + c2] = make_float4(s0, q0, s1, q1);
                    *(float2*)&cs1[rr * LW + c2] = make_float2(l0, l1);
                }
            }
        }
        __syncthreads();

        // ---- Horizontal stage: KS taps over column sums. ----
        float s = 0.f, s2 = 0.f, sl = 0.f;
        const float2* q2 = cs2 + ty * LW + tx;
        const float*  q1 = cs1 + ty * LW + tx;
        #pragma unroll
        for (int mj = 0; mj < KS; ++mj) {
            const float2 q = q2[mj * D];
            s += q.x; s2 += q.y; sl += q1[mj * D];
        }
        const float mu = s * INVK;
        __syncthreads();                 // cs reads done; muP may alias cs2

        muP[ty * 64 + tx] = mu;
        __syncthreads();

        // ---- SAD ----
        if constexpr ((D & 1) == 0) {
            // D even: vertical-pair x horizontal-pair, b64 ladders, 4 px/owner.
            if (ty < 4 && tx < 32) {
                const int cA = 2 * tx;
                const int rA = (D == 2) ? ((ty < 2) ? ty : ty + 2) : ty;
                const int rB = rA + D;
                const float2 mA = *(const float2*)&muP[rA * 64 + cA];
                const float2 mB = *(const float2*)&muP[rB * 64 + cA];
                float a0=0.f,a1=0.f,b0=0.f,b1=0.f;
                const float* bp = sx + rA * LW + cA;
                #pragma unroll
                for (int mj = 0; mj < KS; ++mj) {
                    #pragma unroll
                    for (int t = 0; t <= KS; ++t) {
                        const float2 v = *(const float2*)(bp + mj * D + t * D * LW);
                        if (t < KS) { a0 += fabsf(v.x - mA.x); a1 += fabsf(v.y - mA.y); }
                        if (t >= 1) { b0 += fabsf(v.x - mB.x); b1 += fabsf(v.y - mB.y); }
                    }
                }
                *(float2*)&sadP[rA * 64 + cA] = make_float2(a0, a1);
                *(float2*)&sadP[rB * 64 + cA] = make_float2(b0, b1);
            }
        } else {
            // D=3: R12 b32 pair-walk (odd stride breaks b64 alignment).
            if (ty < 4) {
                const int o = ty;
                if (o != 3) {
                    const int rA = o;
                    const int rB = rA + D;
                    const float muA = muP[rA * 64 + tx];
                    const float muB = muP[rB * 64 + tx];
                    float sadA = 0.f, sadB = 0.f;
                    const float* bp = sx + rA * LW + tx;
                    #pragma unroll
                    for (int mj = 0; mj < KS; ++mj) {
                        const float* cp = bp + mj * D;
                        #pragma unroll
                        for (int t = 0; t <= KS; ++t) {
                            const float v = cp[t * D * LW];
                            if (t < KS) sadA += fabsf(v - muA);
                            if (t >= 1) sadB += fabsf(v - muB);
                        }
                    }
                    sadP[rA * 64 + tx] = sadA;
                    sadP[rB * 64 + tx] = sadB;
                } else {         // leftover rows 6,7: full K walks
                    #pragma unroll
                    for (int rr = 6; rr <= 7; ++rr) {
                        const float mur = muP[rr * 64 + tx];
                        const float* bp = sx + rr * LW + tx;
                        float sd = 0.f;
                        #pragma unroll
                        for (int mi = 0; mi < KS; ++mi)
                            #pragma unroll
                            for (int mj = 0; mj < KS; ++mj)
                                sd += fabsf(bp[mi * D * LW + mj * D] - mur);
                        sadP[rr * 64 + tx] = sd;
                    }
                }
            }
        }
        __syncthreads();
        const float sad = sadP[ty * 64 + tx];

        // ---- Epilogue. ----
        const float energy   = s2 * INVK;
        const float var      = fmaxf(energy - mu * mu, 0.f);
        const float sd       = sqrtf(var * UNB) + EPS;
        const float contrast = var / (sd * sd);
        const float entropy  = -sl * INVK;
        const float homog    = 1.f / (1.f + sad * INVK);
        const size_t fs = (size_t)H * W;
        const size_t ro = (size_t)(h0 + ty) * W;
        float* op = out + (size_t)bc * 4 * fs + w0 + tx;
        __builtin_nontemporal_store((contrast + EPS) * INV_SQRT_E, &op[0 * fs + ro]);
        __builtin_nontemporal_store((energy   + EPS) * INV_SQRT_E, &op[1 * fs + ro]);
        __builtin_nontemporal_store((entropy  + EPS) * INV_SQRT_E, &op[2 * fs + ro]);
        __builtin_nontemporal_store((homog    + EPS) * INV_SQRT_E, &op[3 * fs + ro]);
    }
}

__global__ __launch_bounds__(512, 8) void tex_fused(
    const float* __restrict__ x, float* __restrict__ out, int H, int W)
{
    extern __shared__ __align__(16) char smem[];
    const int dz = blockIdx.z & 3;       // dilation in fast bits: co-resident
    const int bc = blockIdx.z >> 2;      // blocks on a CU mix D1..D4
    const size_t per = (size_t)8 * 4 * H * W;
    switch (dz) {
        case 0: body<4>(x, out + 3 * per, smem, bc, H, W); break;
        case 1: body<3>(x, out + 2 * per, smem, bc, H, W); break;
        case 2: body<2>(x, out + 1 * per, smem, bc, H, W); break;
        default: body<1>(x, out + 0 * per, smem, bc, H, W); break;
    }
}

extern "C" void kernel_launch(void* const* d_in, const int* in_sizes, int n_in,
                              void* d_out, int out_size, void* d_ws, size_t ws_size,
                              hipStream_t stream) {
    const float* x = (const float*)d_in[0];
    float* out = (float*)d_out;

    const int H = 256, W = 256;
    // Per-D LDS (TH=8, PAD=D*D): 2 b32 planes LH*LW*8 + cs2 TH*LW*8 + cs1 TH*LW*4
    //   D=4: LH=40, LW=96: 30720 + 6144 + 3072 = 39936  (max) -> 4 blocks/CU
    //   D=3: LH=26, LW=82: 17056 + 5248 + 2624 = 24928
    //   D=2: LH=16, LW=72:  9216 + 4608 + 2304 = 16128
    //   D=1: LH=10, LW=66:  5280 (register path; cs unused)
    const size_t smem_bytes = 39936;

    dim3 blk(64, 8, 1);
    dim3 grd(W / 64, H / 8, 8 * 4);      // 4 x-tiles, 32 y-tiles, (bc x dz)
    tex_fused<<<grd, blk, smem_bytes, stream>>>(x, out, H, W);
}

// Round 2
// 77.320 us; speedup vs baseline: 1.3121x; 1.3121x over previous
//
#include <hip/hip_runtime.h>
#include <cstddef>

#define EPS 1e-6f
constexpr float INV_SQRT_E = 0.6065306597126334f;  // exp(-0.5*THETA^2), THETA=1

// R15 = R12 base + the two full-wave-count-reducing vectorizations only.
// R14 post-mortem: its SAD b64 used exec-masked half-waves (no wave-instr
// saving) and the 90-deep b64 unroll spilled past the 64-VGPR tier (~2x
// kernel time, R13 signature). Reverted SAD to R12's b32 pair-walk.
//  1. Staging: paired ds_write_b64 to both planes (LW even); float2 global
//     fast-path when PAD even (D=2,4; gw parity = PAD parity).
//  2. Vertical stage: column-PAIR float2 ladders on 3 full waves (was 6),
//     plane-split (sx pass: 8 accums, slg pass: 4) to bound live VGPRs.
//  3. SAD: R12 verbatim — full-wave b32 pair-walk, spill-safe.
// Config: block (64,8), TH=8, LDS 39,936 B -> 4 blocks/CU = 32 waves/CU.
template <int D>
__device__ __forceinline__ void body(const float* __restrict__ x,
                                     float* __restrict__ out,
                                     char* smem, int bc, int H, int W)
{
    constexpr int PAD = D * D;          // halo per side
    constexpr int KS  = 2 * D + 1;      // taps per axis
    constexpr int K   = KS * KS;        // patch size
    constexpr int TW  = 64, TH = 8;
    constexpr int LW  = TW + 2 * PAD;   // always even
    constexpr int LH  = TH + 2 * PAD;
    constexpr int NE  = LH * LW;        // always even
    constexpr int NI2 = (NE + 1023) / 1024;
    constexpr float INVK = 1.0f / (float)K;
    constexpr float UNB  = (float)K / (float)(K - 1);

    float*  sx  = (float*)smem;                 // [NE] v
    float*  slg = sx + NE;                      // [NE] v*log(v+eps)
    float2* cs2 = (float2*)(slg + NE);          // [TH*LW] {col_s, col_s2}
    float*  cs1 = (float*)(cs2 + TH * LW);      // [TH*LW] col_sl
    // Aliased exchange planes (cs2 region is dead after the horizontal stage;
    // needs 4096 B, cs2 has >= 4608 B for D>=2).
    float*  muP  = (float*)cs2;                 // [TH*64]
    float*  sadP = muP + TH * 64;               // [TH*64]

    const int w0 = blockIdx.x * TW;
    const int h0 = blockIdx.y * TH;
    const float* xp = x + (size_t)bc * H * W;
    const int tid = threadIdx.y * 64 + threadIdx.x;

    // ---- Staging: batched global loads (element pairs), b64 LDS writes. ----
    float v0b[NI2], v1b[NI2];
    #pragma unroll
    for (int i = 0; i < NI2; ++i) {
        const int e0 = 2 * (tid + i * 512);
        float v0 = 0.0f, v1 = 0.0f;
        if (e0 < NE) {
            const int r  = e0 / LW;          // e0, LW even -> cc even
            const int cc = e0 - r * LW;
            const int gh = h0 - PAD + r;
            const int gw = w0 - PAD + cc;
            if (gh >= 0 && gh < H) {
                if constexpr ((PAD & 1) == 0) {
                    // gw even: aligned float2 global fast-path
                    if (gw >= 0 && gw + 1 < W) {
                        const float2 v = *(const float2*)&xp[gh * W + gw];
                        v0 = v.x; v1 = v.y;
                    } else {
                        if (gw >= 0 && gw < W)         v0 = xp[gh * W + gw];
                        if (gw + 1 >= 0 && gw + 1 < W) v1 = xp[gh * W + gw + 1];
                    }
                } else {
                    if (gw >= 0 && gw < W)         v0 = xp[gh * W + gw];
                    if (gw + 1 >= 0 && gw + 1 < W) v1 = xp[gh * W + gw + 1];
                }
            }
        }
        v0b[i] = v0; v1b[i] = v1;
    }
    #pragma unroll
    for (int i = 0; i < NI2; ++i) {
        const int e0 = 2 * (tid + i * 512);
        if (e0 < NE) {
            *(float2*)&sx[e0]  = make_float2(v0b[i], v1b[i]);
            *(float2*)&slg[e0] = make_float2(v0b[i] * __logf(v0b[i] + EPS),
                                             v1b[i] * __logf(v1b[i] + EPS));
        }
    }
    __syncthreads();

    const int tx = threadIdx.x;
    const int ty = threadIdx.y;

    if constexpr (K <= 9) {
        // ---- D=1: single pass, taps cached in registers. ----
        const float* bx = sx  + ty * LW + tx;
        const float* bl = slg + ty * LW + tx;
        float s = 0.f, s2 = 0.f, sl = 0.f, ta[K];
        #pragma unroll
        for (int mi = 0; mi < KS; ++mi)
            #pragma unroll
            for (int mj = 0; mj < KS; ++mj) {
                const float v = bx[mi * LW + mj];
                ta[mi * KS + mj] = v;
                s  += v;
                s2  = fmaf(v, v, s2);
                sl += bl[mi * LW + mj];
            }
        const float mu = s * INVK;
        float sad = 0.f;
        #pragma unroll
        for (int i = 0; i < K; ++i) sad += fabsf(ta[i] - mu);

        const float energy   = s2 * INVK;
        const float var      = fmaxf(energy - mu * mu, 0.f);
        const float sd       = sqrtf(var * UNB) + EPS;
        const float contrast = var / (sd * sd);
        const float entropy  = -sl * INVK;
        const float homog    = 1.f / (1.f + sad * INVK);
        const size_t fs = (size_t)H * W;
        const size_t ro = (size_t)(h0 + ty) * W;
        float* op = out + (size_t)bc * 4 * fs + w0 + tx;
        __builtin_nontemporal_store((contrast + EPS) * INV_SQRT_E, &op[0 * fs + ro]);
        __builtin_nontemporal_store((energy   + EPS) * INV_SQRT_E, &op[1 * fs + ro]);
        __builtin_nontemporal_store((entropy  + EPS) * INV_SQRT_E, &op[2 * fs + ro]);
        __builtin_nontemporal_store((homog    + EPS) * INV_SQRT_E, &op[3 * fs + ro]);
        return;
    } else {
        // ---- Vertical stage: column-PAIR (b64) pair-walk, plane-split.
        //  Row pairs: D=2: (0,2)(1,3)(4,6)(5,7)  D=3: (0,3)(1,4)(2,5)+{6,7}
        //  D=4: (0,4)(1,5)(2,6)(3,7)
        constexpr int HW2 = LW / 2;
        if (tid < 4 * HW2) {
            const int p  = tid / HW2;
            const int c2 = (tid - p * HW2) * 2;
            if (!(D == 3 && p == 3)) {
                const int vA = (D == 2) ? ((p < 2) ? p : p + 2) : p;
                const int vB = vA + D;
                // pass 1: sx (sum + sumsq), 8 live accumulators
                const float2* cx = (const float2*)(sx + vA * LW + c2);
                float sA0=0,sA1=0,qA0=0,qA1=0,sB0=0,sB1=0,qB0=0,qB1=0;
                #pragma unroll
                for (int t = 0; t <= KS; ++t) {
                    const float2 v = cx[t * D * HW2];
                    if (t < KS) { sA0 += v.x; sA1 += v.y;
                                  qA0 = fmaf(v.x,v.x,qA0); qA1 = fmaf(v.y,v.y,qA1); }
                    if (t >= 1) { sB0 += v.x; sB1 += v.y;
                                  qB0 = fmaf(v.x,v.x,qB0); qB1 = fmaf(v.y,v.y,qB1); }
                }
                // pass 2: slg, 4 live accumulators
                const float2* cl = (const float2*)(slg + vA * LW + c2);
                float lA0=0,lA1=0,lB0=0,lB1=0;
                #pragma unroll
                for (int t = 0; t <= KS; ++t) {
                    const float2 g = cl[t * D * HW2];
                    if (t < KS) { lA0 += g.x; lA1 += g.y; }
                    if (t >= 1) { lB0 += g.x; lB1 += g.y; }
                }
                *(float4*)&cs2[vA * LW + c2] = make_float4(sA0, qA0, sA1, qA1);
                *(float4*)&cs2[vB * LW + c2] = make_float4(sB0, qB0, sB1, qB1);
                *(float2*)&cs1[vA * LW + c2] = make_float2(lA0, lA1);
                *(float2*)&cs1[vB * LW + c2] = make_float2(lB0, lB1);
            } else {            // D=3 leftover rows 6,7: independent col-pair walks
                #pragma unroll
                for (int rr = 6; rr <= 7; ++rr) {
                    const float2* cx = (const float2*)(sx  + rr * LW + c2);
                    const float2* cl = (const float2*)(slg + rr * LW + c2);
                    float s0=0,s1=0,q0=0,q1=0,l0=0,l1=0;
                    #pragma unroll
                    for (int mi = 0; mi < KS; ++mi) {
                        const float2 v = cx[mi * D * HW2];
                        const float2 g = cl[mi * D * HW2];
                        s0 += v.x; s1 += v.y;
                        q0 = fmaf(v.x,v.x,q0); q1 = fmaf(v.y,v.y,q1);
                        l0 += g.x; l1 += g.y;
                    }
                    *(float4*)&cs2[rr * LW + c2] = make_float4(s0, q0, s1, q1);
                    *(float2*)&cs1[rr * LW + c2] = make_float2(l0, l1);
                }
            }
        }
        __syncthreads();

        // ---- Horizontal stage: KS taps over column sums. ----
        float s = 0.f, s2 = 0.f, sl = 0.f;
        const float2* q2 = cs2 + ty * LW + tx;
        const float*  q1 = cs1 + ty * LW + tx;
        #pragma unroll
        for (int mj = 0; mj < KS; ++mj) {
            const float2 q = q2[mj * D];
            s += q.x; s2 += q.y; sl += q1[mj * D];
        }
        const float mu = s * INVK;
        __syncthreads();                 // cs reads done; muP may alias cs2

        muP[ty * 64 + tx] = mu;
        __syncthreads();

        // ---- SAD: R12 verbatim — full-wave b32 pair-walk (spill-safe). ----
        if (ty < 4) {
            const int o = ty;
            if (!(D == 3 && o == 3)) {
                const int rA = (D == 2) ? ((o < 2) ? o : o + 2) : o;
                const int rB = rA + D;
                const float muA = muP[rA * 64 + tx];
                const float muB = muP[rB * 64 + tx];
                float sadA = 0.f, sadB = 0.f;
                const float* bp = sx + rA * LW + tx;
                #pragma unroll
                for (int mj = 0; mj < KS; ++mj) {
                    const float* cp = bp + mj * D;
                    #pragma unroll
                    for (int t = 0; t <= KS; ++t) {
                        const float v = cp[t * D * LW];
                        if (t < KS) sadA += fabsf(v - muA);
                        if (t >= 1) sadB += fabsf(v - muB);
                    }
                }
                sadP[rA * 64 + tx] = sadA;
                sadP[rB * 64 + tx] = sadB;
            } else {             // D=3 leftover rows 6,7: full K walks
                #pragma unroll
                for (int rr = 6; rr <= 7; ++rr) {
                    const float mur = muP[rr * 64 + tx];
                    const float* bp = sx + rr * LW + tx;
                    float sd = 0.f;
                    #pragma unroll
                    for (int mi = 0; mi < KS; ++mi)
                        #pragma unroll
                        for (int mj = 0; mj < KS; ++mj)
                            sd += fabsf(bp[mi * D * LW + mj * D] - mur);
                    sadP[rr * 64 + tx] = sd;
                }
            }
        }
        __syncthreads();
        const float sad = sadP[ty * 64 + tx];

        // ---- Epilogue. ----
        const float energy   = s2 * INVK;
        const float var      = fmaxf(energy - mu * mu, 0.f);
        const float sd       = sqrtf(var * UNB) + EPS;
        const float contrast = var / (sd * sd);
        const float entropy  = -sl * INVK;
        const float homog    = 1.f / (1.f + sad * INVK);
        const size_t fs = (size_t)H * W;
        const size_t ro = (size_t)(h0 + ty) * W;
        float* op = out + (size_t)bc * 4 * fs + w0 + tx;
        __builtin_nontemporal_store((contrast + EPS) * INV_SQRT_E, &op[0 * fs + ro]);
        __builtin_nontemporal_store((energy   + EPS) * INV_SQRT_E, &op[1 * fs + ro]);
        __builtin_nontemporal_store((entropy  + EPS) * INV_SQRT_E, &op[2 * fs + ro]);
        __builtin_nontemporal_store((homog    + EPS) * INV_SQRT_E, &op[3 * fs + ro]);
    }
}

__global__ __launch_bounds__(512, 8) void tex_fused(
    const float* __restrict__ x, float* __restrict__ out, int H, int W)
{
    extern __shared__ __align__(16) char smem[];
    const int dz = blockIdx.z & 3;       // dilation in fast bits: co-resident
    const int bc = blockIdx.z >> 2;      // blocks on a CU mix D1..D4
    const size_t per = (size_t)8 * 4 * H * W;
    switch (dz) {
        case 0: body<4>(x, out + 3 * per, smem, bc, H, W); break;
        case 1: body<3>(x, out + 2 * per, smem, bc, H, W); break;
        case 2: body<2>(x, out + 1 * per, smem, bc, H, W); break;
        default: body<1>(x, out + 0 * per, smem, bc, H, W); break;
    }
}

extern "C" void kernel_launch(void* const* d_in, const int* in_sizes, int n_in,
                              void* d_out, int out_size, void* d_ws, size_t ws_size,
                              hipStream_t stream) {
    const float* x = (const float*)d_in[0];
    float* out = (float*)d_out;

    const int H = 256, W = 256;
    // Per-D LDS (TH=8, PAD=D*D): 2 b32 planes LH*LW*8 + cs2 TH*LW*8 + cs1 TH*LW*4
    //   D=4: LH=40, LW=96: 30720 + 6144 + 3072 = 39936  (max) -> 4 blocks/CU
    //   D=3: LH=26, LW=82: 17056 + 5248 + 2624 = 24928
    //   D=2: LH=16, LW=72:  9216 + 4608 + 2304 = 16128
    //   D=1: LH=10, LW=66:  5280 (register path; cs unused)
    const size_t smem_bytes = 39936;

    dim3 blk(64, 8, 1);
    dim3 grd(W / 64, H / 8, 8 * 4);      // 4 x-tiles, 32 y-tiles, (bc x dz)
    tex_fused<<<grd, blk, smem_bytes, stream>>>(x, out, H, W);
}